// Round 2
// baseline (7646.527 us; speedup 1.0000x reference)
//
#include <hip/hip_runtime.h>
#include <math.h>

// Problem constants (from reference setup_inputs)
#define B  4
#define T  64
#define F  32
#define N  512
#define H  64
#define KT 4

// phase-1 rows: X taps 1..3 (3*32) + Z taps 1..3 (3*64) = 288
#define ROWS 288
#define NB   16       // output columns per block
#define NCB  (N/NB)   // 32 column-blocks
#define RPT  9        // rows per thread (288 / 32 row-groups)

// combined phase-2 weight matrix: 64 x 384
// rows j: [0,96)   = aW taps 1..3   (k = 1 + j/32, g = j%32)
//         [96,288) = bW taps 1..3   (k = 1 + (j-96)/64, g = (j-96)%64)
//         [288,320)= aW tap 0
//         [320,384)= bW tap 0
#define JW 384

__global__ void init_wc(const float* __restrict__ aW, const float* __restrict__ bW,
                        const float* __restrict__ xB, const float* __restrict__ zB,
                        float* __restrict__ Wc, float* __restrict__ bsum) {
    int idx = blockIdx.x * blockDim.x + threadIdx.x;
    if (idx < H * JW) {
        int h = idx / JW, j = idx % JW;
        float w;
        if (j < 96)       w = aW[(h * KT + (j >> 5) + 1) * F + (j & 31)];
        else if (j < 288) { int jj = j - 96; w = bW[(h * KT + (jj >> 6) + 1) * H + (jj & 63)]; }
        else if (j < 320) w = aW[(h * KT + 0) * F + (j - 288)];
        else              w = bW[(h * KT + 0) * H + (j - 320)];
        Wc[h * JW + j] = w;
    }
    if (idx < H) bsum[idx] = xB[idx] + zB[idx];
}

// One recurrence step. Grid: B * NCB blocks (b major), 512 threads.
__global__ __launch_bounds__(512) void step_kernel(
    const float* __restrict__ x, const float* __restrict__ z0,
    const float* __restrict__ S, const float* __restrict__ Wc,
    const float* __restrict__ bsum, float* __restrict__ out,
    float* __restrict__ XT12,   // [2][B][2][F][N] : X taps 1,2 (double buffered)
    float* __restrict__ ZT12,   // [2][B][2][H][N] : Z taps 1,2 (double buffered)
    float* __restrict__ Z0,     // [3][B][H][N]    : z_t ring (t mod 3)
    int t)
{
    __shared__ float ldsV[ROWS * 18];        // tap-source tile: [row][m 0..15 (+2 pad)]
    __shared__ float ldsT[NB * (JW + 4)];    // staged taps for phase 2: [col][row 0..383]

    const int blk = blockIdx.x;
    const int b   = blk >> 5;       // NCB = 32
    const int cb  = blk & 31;
    const int n0  = cb * NB;
    const int tid = threadIdx.x;
    const int cur = t & 1, prv = cur ^ 1;

    // ------------- phase 1: new taps (1..3) = old taps (0..2) * S_t -------------
    {
        const int ln = tid & 15;     // column within block / m within tile
        const int rg = tid >> 4;     // 0..31 row group
        float acc[RPT];
        #pragma unroll
        for (int j = 0; j < RPT; ++j) acc[j] = 0.f;

        if (t > 0) {
            const float* src[RPT];
            #pragma unroll
            for (int j = 0; j < RPT; ++j) {
                int r = rg + 32 * j;
                const float* p;
                if (r < 32)        p = x + ((size_t)(b * T + (t - 1)) * F + r) * N;
                else if (r < 64)   p = XT12 + (((size_t)(prv * B + b) * 2 + 0) * F + (r - 32)) * N;
                else if (r < 96)   p = XT12 + (((size_t)(prv * B + b) * 2 + 1) * F + (r - 64)) * N;
                else if (r < 160)  p = (t == 1)
                                       ? z0 + ((size_t)b * H + (r - 96)) * N
                                       : Z0 + (((size_t)((t + 1) % 3) * B + b) * H + (r - 96)) * N;
                else if (r < 224)  p = ZT12 + (((size_t)(prv * B + b) * 2 + 0) * H + (r - 160)) * N;
                else               p = ZT12 + (((size_t)(prv * B + b) * 2 + 1) * H + (r - 224)) * N;
                src[j] = p;
            }
            const float* Sbt = S + (size_t)(b * T + t) * N * N;

            for (int mt = 0; mt < 32; ++mt) {
                #pragma unroll
                for (int j = 0; j < RPT; ++j) {
                    int r = rg + 32 * j;
                    ldsV[r * 18 + ln] = src[j][mt * 16 + ln];
                }
                __syncthreads();
                #pragma unroll
                for (int mm = 0; mm < 16; mm += 2) {
                    float s0 = Sbt[(size_t)(mt * 16 + mm) * N + n0 + ln];
                    float s1 = Sbt[(size_t)(mt * 16 + mm + 1) * N + n0 + ln];
                    #pragma unroll
                    for (int j = 0; j < RPT; ++j) {
                        const float2 v = *reinterpret_cast<const float2*>(
                            &ldsV[(rg + 32 * j) * 18 + mm]);
                        acc[j] += v.x * s0 + v.y * s1;
                    }
                }
                __syncthreads();
            }
        }

        // stage computed taps to LDS rows 0..287; persist taps 1,2 to global
        #pragma unroll
        for (int j = 0; j < RPT; ++j) {
            int r = rg + 32 * j;
            float v = acc[j];
            ldsT[ln * (JW + 4) + r] = v;
            int n = n0 + ln;
            if (r < 32)        XT12[(((size_t)(cur * B + b) * 2 + 0) * F + r) * N + n] = v;
            else if (r < 64)   XT12[(((size_t)(cur * B + b) * 2 + 1) * F + (r - 32)) * N + n] = v;
            else if (r < 96)   { /* X tap3: LDS only */ }
            else if (r < 160)  ZT12[(((size_t)(cur * B + b) * 2 + 0) * H + (r - 96)) * N + n] = v;
            else if (r < 224)  ZT12[(((size_t)(cur * B + b) * 2 + 1) * H + (r - 160)) * N + n] = v;
            /* Z tap3: LDS only */
        }
        // stage rows 288..383: Xtap0 = x[b,t], Ztap0 = z_{t-1}
        #pragma unroll
        for (int j = 0; j < 3; ++j) {
            int re = rg + 32 * j;   // 0..95
            float v;
            if (re < 32) {
                v = x[((size_t)(b * T + t) * F + re) * N + n0 + ln];
            } else {
                int hh = re - 32;
                v = (t == 0)
                    ? z0[((size_t)b * H + hh) * N + n0 + ln]
                    : Z0[(((size_t)((t + 2) % 3) * B + b) * H + hh) * N + n0 + ln];
            }
            ldsT[ln * (JW + 4) + 288 + re] = v;
        }
    }
    __syncthreads();

    // ------------- phase 2: z_t = tanh(Wc . taps + bias) -------------
    {
        const int h  = tid >> 3;   // 0..63
        const int nc = tid & 7;    // 2 cols: nc and nc+8
        const float4* Wrow = reinterpret_cast<const float4*>(Wc + (size_t)h * JW);
        const float4* tA   = reinterpret_cast<const float4*>(&ldsT[nc * (JW + 4)]);
        const float4* tB   = reinterpret_cast<const float4*>(&ldsT[(nc + 8) * (JW + 4)]);
        float u0 = 0.f, u1 = 0.f;
        #pragma unroll 8
        for (int q = 0; q < JW / 4; ++q) {
            float4 w  = Wrow[q];
            float4 a  = tA[q];
            float4 bb = tB[q];
            u0 += w.x * a.x  + w.y * a.y  + w.z * a.z  + w.w * a.w;
            u1 += w.x * bb.x + w.y * bb.y + w.z * bb.z + w.w * bb.w;
        }
        float bs = bsum[h];
        float za = tanhf(u0 + bs);
        float zb = tanhf(u1 + bs);
        size_t obase = ((size_t)(b * T + t) * H + h) * N + n0;
        out[obase + nc]     = za;
        out[obase + nc + 8] = zb;
        size_t zbase = (((size_t)(t % 3) * B + b) * H + h) * N + n0;
        Z0[zbase + nc]     = za;
        Z0[zbase + nc + 8] = zb;
    }
}

extern "C" void kernel_launch(void* const* d_in, const int* in_sizes, int n_in,
                              void* d_out, int out_size, void* d_ws, size_t ws_size,
                              hipStream_t stream) {
    const float* x  = (const float*)d_in[0];
    const float* z0 = (const float*)d_in[1];
    const float* S  = (const float*)d_in[2];
    const float* aW = (const float*)d_in[3];
    const float* bW = (const float*)d_in[4];
    const float* xB = (const float*)d_in[5];
    const float* zB = (const float*)d_in[6];
    float* out = (float*)d_out;
    float* ws  = (float*)d_ws;

    float* XT12 = ws;                                 // 2*B*2*F*N = 262144 floats
    float* ZT12 = XT12 + (size_t)2 * B * 2 * F * N;   // 524288 floats
    float* Z0   = ZT12 + (size_t)2 * B * 2 * H * N;   // 393216 floats
    float* Wc   = Z0   + (size_t)3 * B * H * N;       // 24576 floats
    float* bsum = Wc   + (size_t)H * JW;              // 64 floats

    init_wc<<<96, 256, 0, stream>>>(aW, bW, xB, zB, Wc, bsum);
    for (int t = 0; t < T; ++t) {
        step_kernel<<<B * NCB, 512, 0, stream>>>(x, z0, S, Wc, bsum, out,
                                                 XT12, ZT12, Z0, t);
    }
}

// Round 3
// 2463.263 us; speedup vs baseline: 3.1042x; 3.1042x over previous
//
#include <hip/hip_runtime.h>
#include <math.h>

#define B_  4
#define T_  64
#define F_  32
#define N_  512
#define H_  64

#define CN     32              // output columns per block
#define NCB    (N_/CN)         // 16 col-blocks
#define AROWS  288             // phase-1 rows (taps 0..2 producing 1..3)
#define JW     384             // phase-2 reduction length
#define NWAVES 9
#define NTHR   (NWAVES*64)

typedef __attribute__((ext_vector_type(8))) short short8;
typedef __attribute__((ext_vector_type(4))) float float4_;
typedef unsigned short u16;
typedef unsigned int   u32;

__device__ __host__ inline u16 f2bf(float x) {
    union { float f; u32 u; } v; v.f = x;
    u32 r = v.u + 0x7fff + ((v.u >> 16) & 1);
    return (u16)(r >> 16);
}
__device__ inline float bf2f(u16 h) {
    union { float f; u32 u; } v; v.u = ((u32)h) << 16;
    return v.f;
}

// Wc row mapping (phase-2 k index r):
//  0..95   aW taps 1..3   96..287 bW taps 1..3
//  288..319 aW tap0       320..383 bW tap0
__global__ void init_wc(const float* __restrict__ aW, const float* __restrict__ bW,
                        const float* __restrict__ xB, const float* __restrict__ zB,
                        u16* __restrict__ Wch, u16* __restrict__ Wcl,
                        float* __restrict__ bsum) {
    int idx = blockIdx.x * blockDim.x + threadIdx.x;
    if (idx < H_ * JW) {
        int h = idx / JW, j = idx % JW;
        float w;
        if (j < 96)       w = aW[(h*4 + (j>>5) + 1)*F_ + (j&31)];
        else if (j < 288) { int jj = j - 96; w = bW[(h*4 + (jj>>6) + 1)*H_ + (jj&63)]; }
        else if (j < 320) w = aW[(h*4)*F_ + (j - 288)];
        else              w = bW[(h*4)*H_ + (j - 320)];
        u16 hi = f2bf(w);
        Wch[idx] = hi;
        Wcl[idx] = f2bf(w - bf2f(hi));
    }
    if (idx < H_) bsum[idx] = xB[idx] + zB[idx];
}

// A layout per b (rows of the matrix multiplied by S_t at step t):
//  0..31  Xtap0(t-1)=x_{t-1}   32..95  Xtap1,2(t-1)
//  96..159 Ztap0(t-1)=z_{t-2}  160..287 Ztap1,2(t-1)
// C = A*S_t rows: 0..95 = Xtap1..3(t), 96..287 = Ztap1..3(t)
__global__ __launch_bounds__(NTHR) void step_kernel(
    const float* __restrict__ x, const float* __restrict__ z0,
    const float* __restrict__ S,
    const u16* __restrict__ Wch, const u16* __restrict__ Wcl,
    const float* __restrict__ bsum, float* __restrict__ out,
    const u16* __restrict__ Aph, const u16* __restrict__ Apl,
    u16* __restrict__ Anh, u16* __restrict__ Anl,
    int t)
{
    // Slds: [buf][hi/lo][n(32)][k(32)+pad8]  (u16, pitch 40 -> 80B, 16B-aligned)
    __shared__ __align__(16) u16 Slds[2][2][CN][40];
    // Clds: [hi/lo][n(32)][row-pair rp(192)+pad4] (u32 = rows {2rp,2rp+1})
    __shared__ __align__(16) u32 Clds[2][CN][196];

    const int tid  = threadIdx.x;
    const int wave = tid >> 6;
    const int lane = tid & 63;
    const int c16  = lane & 15;
    const int g4   = lane >> 4;

    const int b  = blockIdx.x & 3;          // same-b blocks land on 2 XCDs
    const int cb = blockIdx.x >> 2;
    const int n0 = cb * CN;

    const float* Sbt = S + (size_t)(b*T_ + t) * N_ * N_;

    // ---- stage x_t (rows 288..319) and z_{t-1} (rows 320..383) into Clds;
    //      also write A_next rows 0..31 (x_t) and 96..159 (z_{t-1})
    if (tid < 512) {
        const int col = tid & 31;
        const int rb  = (tid >> 5) * 6;
        #pragma unroll
        for (int j = 0; j < 6; ++j) {
            int row = rb + j;               // 0..95
            float v; int arow;
            if (row < 32) {
                v = x[((size_t)(b*T_ + t)*F_ + row) * N_ + n0 + col];
                arow = row;
            } else {
                int hz = row - 32;
                v = (t == 0)
                    ? z0[((size_t)b*H_ + hz) * N_ + n0 + col]
                    : out[((size_t)(b*T_ + (t-1))*H_ + hz) * N_ + n0 + col];
                arow = 96 + hz;
            }
            u16 hi = f2bf(v);
            u16 lo = f2bf(v - bf2f(hi));
            ((u16*)&Clds[0][col][0])[288 + row] = hi;
            ((u16*)&Clds[1][col][0])[288 + row] = lo;
            size_t ai = ((size_t)b*AROWS + arow) * N_ + n0 + col;
            Anh[ai] = hi; Anl[ai] = lo;
        }
    }

    if (t == 0) {
        // zero tap rows of Clds (rows 0..287 -> rp 0..143) and A_next computed rows
        for (int i = tid; i < CN*144; i += NTHR) {
            int n = i / 144, rp = i % 144;
            Clds[0][n][rp] = 0; Clds[1][n][rp] = 0;
        }
        for (int i = tid; i < 192*(CN/2); i += NTHR) {
            int r = i / (CN/2), c2 = i % (CN/2);
            int arow = (r < 64) ? 32 + r : 96 + r;   // 32..95, 160..287
            size_t ai = ((size_t)b*AROWS + arow) * N_ + n0;
            ((u32*)(Anh + ai))[c2] = 0;
            ((u32*)(Anl + ai))[c2] = 0;
        }
    } else {
        // ================= phase 1: C[288xCN] = A * S_t  (bf16x3 MFMA) =================
        const int r0 = wave * 32;
        const u16* Ah0 = Aph + ((size_t)b*AROWS + r0 + c16) * N_;
        const u16* Al0 = Apl + ((size_t)b*AROWS + r0 + c16) * N_;

        auto stage = [&](int ks, int buf) {
            if (tid < 512) {
                int col = tid & 31;
                int rbase = tid >> 5;       // 0..15
                #pragma unroll
                for (int hh = 0; hh < 2; ++hh) {
                    int row = rbase + 16*hh;
                    float v = Sbt[(size_t)(ks*32 + row) * N_ + n0 + col];
                    u16 hi = f2bf(v);
                    u16 lo = f2bf(v - bf2f(hi));
                    Slds[buf][0][col][row] = hi;
                    Slds[buf][1][col][row] = lo;
                }
            }
        };

        float4_ acc[2][2];
        #pragma unroll
        for (int i = 0; i < 2; ++i)
            #pragma unroll
            for (int j = 0; j < 2; ++j) acc[i][j] = (float4_){0.f,0.f,0.f,0.f};

        stage(0, 0);
        short8 ah[2], al[2];
        #pragma unroll
        for (int rf = 0; rf < 2; ++rf) {
            ah[rf] = *(const short8*)(Ah0 + (size_t)rf*16*N_ + g4*8);
            al[rf] = *(const short8*)(Al0 + (size_t)rf*16*N_ + g4*8);
        }
        __syncthreads();

        for (int ks = 0; ks < 16; ++ks) {
            const int buf = ks & 1;
            if (ks < 15) stage(ks + 1, buf ^ 1);
            short8 ahn[2], aln[2];
            if (ks < 15) {
                #pragma unroll
                for (int rf = 0; rf < 2; ++rf) {
                    ahn[rf] = *(const short8*)(Ah0 + (size_t)rf*16*N_ + (ks+1)*32 + g4*8);
                    aln[rf] = *(const short8*)(Al0 + (size_t)rf*16*N_ + (ks+1)*32 + g4*8);
                }
            }
            short8 bh[2], bl[2];
            #pragma unroll
            for (int nf = 0; nf < 2; ++nf) {
                bh[nf] = *(const short8*)&Slds[buf][0][nf*16 + c16][g4*8];
                bl[nf] = *(const short8*)&Slds[buf][1][nf*16 + c16][g4*8];
            }
            #pragma unroll
            for (int rf = 0; rf < 2; ++rf)
                #pragma unroll
                for (int nf = 0; nf < 2; ++nf) {
                    acc[rf][nf] = __builtin_amdgcn_mfma_f32_16x16x32_bf16(ah[rf], bh[nf], acc[rf][nf], 0,0,0);
                    acc[rf][nf] = __builtin_amdgcn_mfma_f32_16x16x32_bf16(ah[rf], bl[nf], acc[rf][nf], 0,0,0);
                    acc[rf][nf] = __builtin_amdgcn_mfma_f32_16x16x32_bf16(al[rf], bh[nf], acc[rf][nf], 0,0,0);
                }
            if (ks < 15) {
                ah[0]=ahn[0]; ah[1]=ahn[1]; al[0]=aln[0]; al[1]=aln[1];
            }
            __syncthreads();
        }

        // ---- C epilogue: split hi/lo, write Clds rows r0.. and A_next persisted rows
        // wave-uniform A_next offset: waves 0,1 -> +32 ; waves 3..6 -> +64 ; else skip
        const int aoff = (wave < 2) ? 32 : (wave >= 3 && wave <= 6) ? 64 : -1;
        #pragma unroll
        for (int rf = 0; rf < 2; ++rf) {
            int crow = r0 + rf*16 + g4*4;          // + reg r (0..3)
            int rp   = crow >> 1;                  // even base
            #pragma unroll
            for (int nf = 0; nf < 2; ++nf) {
                int n = nf*16 + c16;
                float4_ a = acc[rf][nf];
                u16 h0=f2bf(a.x), h1=f2bf(a.y), h2=f2bf(a.z), h3=f2bf(a.w);
                u16 l0=f2bf(a.x - bf2f(h0)), l1=f2bf(a.y - bf2f(h1));
                u16 l2=f2bf(a.z - bf2f(h2)), l3=f2bf(a.w - bf2f(h3));
                Clds[0][n][rp]   = (u32)h0 | ((u32)h1 << 16);
                Clds[0][n][rp+1] = (u32)h2 | ((u32)h3 << 16);
                Clds[1][n][rp]   = (u32)l0 | ((u32)l1 << 16);
                Clds[1][n][rp+1] = (u32)l2 | ((u32)l3 << 16);
                if (aoff > 0) {
                    size_t base = ((size_t)b*AROWS + crow + aoff) * N_ + n0 + n;
                    Anh[base]        = h0; Anl[base]        = l0;
                    Anh[base +   N_] = h1; Anl[base +   N_] = l1;
                    Anh[base + 2*N_] = h2; Anl[base + 2*N_] = l2;
                    Anh[base + 3*N_] = h3; Anl[base + 3*N_] = l3;
                }
            }
        }
    }
    __syncthreads();

    // ================= phase 2: z = tanh(Wc * taps2 + bias)  (bf16x3 MFMA) =================
    if (wave < 8) {
        const int hf = wave >> 1;
        const int nf = wave & 1;
        float4_ a2 = (float4_){0.f,0.f,0.f,0.f};
        const u16* Wh0 = Wch + (size_t)(hf*16 + c16) * JW;
        const u16* Wl0 = Wcl + (size_t)(hf*16 + c16) * JW;
        const u16* Th = (const u16*)&Clds[0][nf*16 + c16][0];
        const u16* Tl = (const u16*)&Clds[1][nf*16 + c16][0];
        #pragma unroll 4
        for (int kf = 0; kf < 12; ++kf) {
            short8 wh = *(const short8*)(Wh0 + kf*32 + g4*8);
            short8 wl = *(const short8*)(Wl0 + kf*32 + g4*8);
            short8 th = *(const short8*)(Th + kf*32 + g4*8);
            short8 tl = *(const short8*)(Tl + kf*32 + g4*8);
            a2 = __builtin_amdgcn_mfma_f32_16x16x32_bf16(wh, th, a2, 0,0,0);
            a2 = __builtin_amdgcn_mfma_f32_16x16x32_bf16(wh, tl, a2, 0,0,0);
            a2 = __builtin_amdgcn_mfma_f32_16x16x32_bf16(wl, th, a2, 0,0,0);
        }
        const int h0r = hf*16 + g4*4;
        const float4 bsv = *(const float4*)(bsum + h0r);
        float zx = tanhf(a2.x + bsv.x);
        float zy = tanhf(a2.y + bsv.y);
        float zz = tanhf(a2.z + bsv.z);
        float zw = tanhf(a2.w + bsv.w);
        size_t ob = ((size_t)(b*T_ + t)*H_ + h0r) * N_ + n0 + nf*16 + c16;
        out[ob]        = zx;
        out[ob +   N_] = zy;
        out[ob + 2*N_] = zz;
        out[ob + 3*N_] = zw;
    }
}

extern "C" void kernel_launch(void* const* d_in, const int* in_sizes, int n_in,
                              void* d_out, int out_size, void* d_ws, size_t ws_size,
                              hipStream_t stream) {
    const float* x  = (const float*)d_in[0];
    const float* z0 = (const float*)d_in[1];
    const float* S  = (const float*)d_in[2];
    const float* aW = (const float*)d_in[3];
    const float* bW = (const float*)d_in[4];
    const float* xB = (const float*)d_in[5];
    const float* zB = (const float*)d_in[6];
    float* out = (float*)d_out;

    char* p = (char*)d_ws;
    u16*   Wch  = (u16*)p;   p += (size_t)H_*JW*2;      // 49152
    u16*   Wcl  = (u16*)p;   p += (size_t)H_*JW*2;
    float* bsum = (float*)p; p += 256;
    const size_t asz = (size_t)B_*AROWS*N_*2;           // 1179648 B
    u16* Ah[2]; u16* Al[2];
    Ah[0] = (u16*)p; p += asz;
    Al[0] = (u16*)p; p += asz;
    Ah[1] = (u16*)p; p += asz;
    Al[1] = (u16*)p; p += asz;

    init_wc<<<96, 256, 0, stream>>>(aW, bW, xB, zB, Wch, Wcl, bsum);
    for (int t = 0; t < T_; ++t) {
        const int pb = t & 1, nb = pb ^ 1;
        step_kernel<<<B_*NCB, NTHR, 0, stream>>>(x, z0, S, Wch, Wcl, bsum, out,
                                                 Ah[pb], Al[pb], Ah[nb], Al[nb], t);
    }
}